// Round 1
// baseline (1217.409 us; speedup 1.0000x reference)
//
#include <hip/hip_runtime.h>
#include <cstdint>
#include <cstddef>

// Problem constants
#define B_   8
#define NM_  10
#define T_   16376
#define D_   512
#define H_   8
#define DH_  64
#define L_   4
#define S_   2048
#define NB_  32
#define BS_  64
#define FF_  2048
#define MTOK (B_*S_)   // 16384 token rows
#define DD_  (D_*D_)
#define KE_  128       // embed K padded (80 -> 128, divisible by BK=64)

typedef __attribute__((ext_vector_type(8))) __bf16 bf16x8;
typedef __attribute__((ext_vector_type(4))) __bf16 bf16x4;
typedef __attribute__((ext_vector_type(4))) float f32x4;

__device__ __forceinline__ void async16(void* lds, const void* g) {
    __builtin_amdgcn_global_load_lds(
        (const __attribute__((address_space(1))) void*)g,
        (__attribute__((address_space(3))) void*)lds, 16, 0, 0);
}

// XOR-swizzled 16B-chunk index for a row x 64el bf16 tile (8 chunks/row).
#define SWZ64(row, kq) (((row) << 3) + ((kq) ^ ((row) & 7)))

// ---------------------------------------------------------------------------
// Weight transpose+convert: in (K x N fp32) -> out (N x Kp bf16), zero-pad
// k in [K, Kp). Grid: (N/32, Kp/32, Z) with z-strided in/out.
// ---------------------------------------------------------------------------
__global__ __launch_bounds__(256) void wconv_kernel(
    const float* __restrict__ in, __bf16* __restrict__ outp, int K, int N, int Kp)
{
    __shared__ float t[32][33];
    const float* ip = in + (size_t)blockIdx.z * K * N;
    __bf16* op = outp + (size_t)blockIdx.z * N * Kp;
    int n0 = blockIdx.x * 32, k0 = blockIdx.y * 32;
    int tx = threadIdx.x, ty = threadIdx.y;   // 32 x 8
    #pragma unroll
    for (int j = 0; j < 4; j++) {
        int k = k0 + ty + 8 * j;
        t[ty + 8 * j][tx] = (k < K) ? ip[(size_t)k * N + n0 + tx] : 0.f;
    }
    __syncthreads();
    #pragma unroll
    for (int j = 0; j < 4; j++)
        op[(size_t)(n0 + ty + 8 * j) * Kp + k0 + tx] = (__bf16)t[tx][ty + 8 * j];
}

// Merged Wq/Wk/Wv/Wo transpose (all D_ x D_). Grid (16,16,16): z = mat*4+layer.
__global__ __launch_bounds__(256) void wconv_qkvo(
    const float* __restrict__ wq, const float* __restrict__ wk,
    const float* __restrict__ wv, const float* __restrict__ wo,
    __bf16* __restrict__ wtqkv, __bf16* __restrict__ wto)
{
    __shared__ float t[32][33];
    int zz = blockIdx.z;
    int mat = zz >> 2, layer = zz & 3;
    const float* src = (mat == 0 ? wq : mat == 1 ? wk : mat == 2 ? wv : wo)
                       + (size_t)layer * DD_;
    __bf16* dst = (mat < 3) ? wtqkv + ((size_t)mat * L_ + layer) * DD_
                            : wto + (size_t)layer * DD_;
    int n0 = blockIdx.x * 32, k0 = blockIdx.y * 32;
    int tx = threadIdx.x, ty = threadIdx.y;   // 32 x 8
    #pragma unroll
    for (int j = 0; j < 4; j++)
        t[ty + 8 * j][tx] = src[(size_t)(k0 + ty + 8 * j) * D_ + n0 + tx];
    __syncthreads();
    #pragma unroll
    for (int j = 0; j < 4; j++)
        dst[(size_t)(n0 + ty + 8 * j) * D_ + k0 + tx] = (__bf16)t[tx][ty + 8 * j];
}

// ---------------------------------------------------------------------------
// Build xr (MTOK x KE_ bf16): xr[b*2048+t][m] = x[b, m/8, (m%8)*2047 + t-1]
// for t>=1, m<80; else 0. One block per 64 rows (same b).
// ---------------------------------------------------------------------------
__global__ __launch_bounds__(256) void xbuild_kernel(
    const float* __restrict__ x, __bf16* __restrict__ xr)
{
    __shared__ float xs[64][KE_ + 1];
    int row0 = blockIdx.x * 64;
    int b = row0 >> 11;
    int t0 = row0 & (S_ - 1);
    int tid = threadIdx.x;
    int lane = tid & 63;
    int mq = tid >> 6;          // 0..3
    for (int mb = 0; mb < 32; mb++) {
        int m = mb * 4 + mq;    // 0..127
        int t = t0 + lane;
        float v = 0.f;
        if (m < 80 && t > 0)
            v = x[(size_t)b * NM_ * T_ + (size_t)(m >> 3) * T_ + (m & 7) * 2047 + (t - 1)];
        xs[lane][m] = v;
    }
    __syncthreads();
    #pragma unroll
    for (int u = 0; u < 8; u++) {
        int ch = tid + u * 256;          // 0..2047
        int row = ch >> 5, c4 = (ch & 31) * 4;
        bf16x4 pk;
        #pragma unroll
        for (int i = 0; i < 4; i++) pk[i] = (__bf16)xs[row][c4 + i];
        *(bf16x4*)&xr[(size_t)(row0 + row) * KE_ + c4] = pk;
    }
}

// ---------------------------------------------------------------------------
// MFMA bf16 GEMM: C = A(MxK bf16) @ Wt^T + bias [+pe] [relu]
// Wt is N x K bf16 (pre-transposed). BM=256 x BN=128 tile, BK=64,
// 512 thr (8 waves, each owning a 64x64 output sub-tile).
// TRIPLE-buffered LDS (144 KiB) + counted vmcnt: while computing tile t,
// tile t+2 is issued; the per-tile boundary waits vmcnt(6) (tile t+1 landed,
// tile t+2's 6 loads still in flight) via raw inline-asm + s_barrier so the
// compiler cannot re-insert the vmcnt(0) drain. One barrier per K-tile.
// XOR swizzle for conflict-free ds_read_b128; XCD-aware block swizzle.
// Epilogue identical to previous version (bias/relu/pe/scatter/Cf/Cb).
// ---------------------------------------------------------------------------
__global__ __launch_bounds__(512, 2) void mfma_gemm(
    const __bf16* __restrict__ A, const __bf16* __restrict__ Wt,
    const float* __restrict__ bias0, const float* __restrict__ bias1,
    const float* __restrict__ bias2,
    const float* __restrict__ pe, float* __restrict__ Cf, __bf16* __restrict__ Cb,
    int N, int K, long wtz, long cbz, int relu, int scatter, int nz)
{
    __shared__ __align__(16) __bf16 As[3 * 256 * 64];   // 96 KiB
    __shared__ __align__(16) __bf16 Bs[3 * 128 * 64];   // 48 KiB
    int tid = threadIdx.x;
    int wave = tid >> 6;
    int lane = tid & 63;

    int nbx = gridDim.x, nby = gridDim.y;
    int bxIdx, bmIdx;
    if ((nby & 7) == 0) {
        int id = blockIdx.y * nbx + blockIdx.x;   // dispatch-linear order
        int chunk = nby >> 3;
        int xcd = id & 7;
        int local = id >> 3;
        int row = local / nbx;
        bmIdx = xcd * chunk + row;
        bxIdx = local - row * nbx;
    } else {
        bxIdx = blockIdx.x; bmIdx = blockIdx.y;
    }
    int z = bxIdx % nz;
    int bn = (bxIdx / nz) * 128;
    int bm = bmIdx * 256;
    const __bf16* Wz = Wt + (size_t)z * wtz;
    const float* bias = (z == 0) ? bias0 : (z == 1 ? bias1 : bias2);

    f32x4 acc[4][4];
    #pragma unroll
    for (int r = 0; r < 4; r++)
        #pragma unroll
        for (int c = 0; c < 4; c++) acc[r][c] = (f32x4){0.f, 0.f, 0.f, 0.f};

    const int wr = (wave >> 1) * 64;   // 0..192 (row band within 256)
    const int wc = (wave & 1) * 64;    // 0/64   (col band within 128)
    const int fr = lane & 15;
    const int kqi = lane >> 4;   // 0..3

    // staging addresses: pre-swizzled global source, linear LDS dest
    const __bf16* pA[4];
    const __bf16* pB[2];
    int ldsA[4], ldsB[2];
    #pragma unroll
    for (int u = 0; u < 4; u++) {
        int p = tid + 512 * u;          // chunk 0..2047 (A: 256 rows x 8 chunks)
        int row = p >> 3;
        int kq = (p & 7) ^ (row & 7);
        pA[u] = A + (size_t)(bm + row) * K + kq * 8;
        ldsA[u] = (u * 512 + wave * 64) * 8;   // wave-uniform base (elems)
    }
    #pragma unroll
    for (int u = 0; u < 2; u++) {
        int p = tid + 512 * u;          // chunk 0..1023 (B: 128 rows x 8 chunks)
        int row = p >> 3;
        int kq = (p & 7) ^ (row & 7);
        pB[u] = Wz + (size_t)(bn + row) * K + kq * 8;
        ldsB[u] = (u * 512 + wave * 64) * 8;
    }

    __bf16 *a0 = As, *a1 = As + 256 * 64, *a2 = As + 2 * 256 * 64;
    __bf16 *b0 = Bs, *b1 = Bs + 128 * 64, *b2 = Bs + 2 * 128 * 64;

    // prologue: stage tiles 0 and 1 (issue order matters for vmcnt counting)
    #pragma unroll
    for (int u = 0; u < 4; u++) async16(a0 + ldsA[u], pA[u]);
    #pragma unroll
    for (int u = 0; u < 2; u++) async16(b0 + ldsB[u], pB[u]);
    asm volatile("" ::: "memory");   // keep tile-0 issues before tile-1 issues
    #pragma unroll
    for (int u = 0; u < 4; u++) async16(a1 + ldsA[u], pA[u] + 64);
    #pragma unroll
    for (int u = 0; u < 2; u++) async16(b1 + ldsB[u], pB[u] + 64);
    // tile 0 landed (6 of tile 1 still in flight)
    asm volatile("s_waitcnt vmcnt(6)\n\ts_barrier" ::: "memory");

    const int NT = K >> 6;
    for (int t = 0; t < NT; ++t) {
        if (t + 2 < NT) {
            int kk = (t + 2) * 64;
            #pragma unroll
            for (int u = 0; u < 4; u++) async16(a2 + ldsA[u], pA[u] + kk);
            #pragma unroll
            for (int u = 0; u < 2; u++) async16(b2 + ldsB[u], pB[u] + kk);
        }
        #pragma unroll
        for (int ks = 0; ks < 2; ks++) {
            int kq0 = ks * 4 + kqi;
            bf16x8 af[4], bfr[4];
            #pragma unroll
            for (int r = 0; r < 4; r++)
                af[r] = *(const bf16x8*)&a0[SWZ64(wr + r * 16 + fr, kq0) * 8];
            #pragma unroll
            for (int c = 0; c < 4; c++)
                bfr[c] = *(const bf16x8*)&b0[SWZ64(wc + c * 16 + fr, kq0) * 8];
            __builtin_amdgcn_s_setprio(1);
            #pragma unroll
            for (int r = 0; r < 4; r++)
                #pragma unroll
                for (int c = 0; c < 4; c++)
                    acc[r][c] = __builtin_amdgcn_mfma_f32_16x16x32_bf16(af[r], bfr[c], acc[r][c], 0, 0, 0);
            __builtin_amdgcn_s_setprio(0);
        }
        // boundary: tile t+1 must have landed; keep tile t+2's 6 loads in flight
        if (t + 2 < NT) asm volatile("s_waitcnt vmcnt(6)\n\ts_barrier" ::: "memory");
        else            asm volatile("s_waitcnt vmcnt(0)\n\ts_barrier" ::: "memory");
        __bf16* ta = a0; a0 = a1; a1 = a2; a2 = ta;
        __bf16* tb = b0; b0 = b1; b1 = b2; b2 = tb;
    }

    // epilogue: C/D layout col = lane&15, row = (lane>>4)*4 + reg
    int rbase = bm + wr + (lane >> 4) * 4;
    #pragma unroll
    for (int c = 0; c < 4; c++) {
        int cg = bn + wc + c * 16 + fr;
        float bv = bias[cg];
        #pragma unroll
        for (int r = 0; r < 4; r++) {
            int rg0 = rbase + r * 16;   // 4-aligned
            float vals[4];
            #pragma unroll
            for (int i = 0; i < 4; i++) {
                float val = acc[r][c][i] + bv;
                if (relu) val = fmaxf(val, 0.f);
                if (pe) {
                    int t = (rg0 + i) & (S_ - 1);
                    val = (t == 0) ? pe[cg] : val + pe[(size_t)t * N + cg];
                }
                vals[i] = val;
            }
            if (Cf) {
                #pragma unroll
                for (int i = 0; i < 4; i++) Cf[(size_t)(rg0 + i) * N + cg] = vals[i];
            }
            if (Cb) {
                if (scatter) {
                    int bb = rg0 >> 11;
                    int s0 = rg0 & (S_ - 1);
                    int hh = cg >> 6, dh = cg & 63;
                    if (z == 2) {
                        bf16x4 pk;
                        #pragma unroll
                        for (int i = 0; i < 4; i++) pk[i] = (__bf16)vals[i];
                        *(bf16x4*)(Cb + (size_t)z * cbz +
                                   ((((size_t)bb * H_ + hh) * DH_ + dh) * S_) + s0) = pk;
                    } else {
                        #pragma unroll
                        for (int i = 0; i < 4; i++)
                            (Cb + (size_t)z * cbz)[((((size_t)bb * H_ + hh) * S_ + s0 + i) * DH_) + dh] = (__bf16)vals[i];
                    }
                } else {
                    #pragma unroll
                    for (int i = 0; i < 4; i++) Cb[(size_t)(rg0 + i) * N + cg] = (__bf16)vals[i];
                }
            }
        }
    }
}

// ---------------------------------------------------------------------------
// MFMA block-sparse attention. One workgroup (4 waves) per (b,h,n); each wave
// owns 16 q-rows. XCD affinity: all 32 n-blocks of one (b,h) on one XCD.
// ---------------------------------------------------------------------------
#define KSTR 72
__global__ __launch_bounds__(256, 4) void attn_kernel(
    const __bf16* __restrict__ q, const __bf16* __restrict__ k,
    const __bf16* __restrict__ vt, const int* __restrict__ rb,
    __bf16* __restrict__ o)
{
    __shared__ __align__(16) __bf16 Ks[64 * KSTR];
    __shared__ __align__(16) __bf16 Vs[64 * KSTR];
    __shared__ __align__(16) __bf16 Ps[64 * KSTR];
    int bid = blockIdx.x;                 // 2048
    int xcd = bid & 7;
    int local = bid >> 3;                 // 0..255
    int bh = (local >> 5) * 8 + xcd;      // 0..63, fixed per XCD
    int n = local & 31;
    int b = bh >> 3;
    int hh = bh & 7;
    int tid = threadIdx.x;
    int wave = tid >> 6;
    int lane = tid & 63;
    const int fr = lane & 15;
    const int fq = lane >> 4;

    int idx[6];
    idx[0] = 0;
    idx[1] = n > 0 ? n - 1 : 0;
    idx[2] = n;
    idx[3] = n < NB_ - 1 ? n + 1 : NB_ - 1;
    idx[4] = rb[n * 2 + 0];
    idx[5] = rb[n * 2 + 1];

    const size_t plane = ((size_t)b * H_ + hh) * S_;
    const __bf16* vtb = vt + plane * DH_;

    const __bf16* qrow = q + (plane + (size_t)n * BS_ + wave * 16 + fr) * DH_ + fq * 8;
    bf16x8 qf0 = *(const bf16x8*)qrow;
    bf16x8 qf1 = *(const bf16x8*)(qrow + 32);

    f32x4 oacc[4];
    #pragma unroll
    for (int dt = 0; dt < 4; dt++) oacc[dt] = (f32x4){0.f, 0.f, 0.f, 0.f};
    float mrow = -1e30f, lrow = 0.f;

    for (int c = 0; c < 6; c++) {
        bool dup = false;
        #pragma unroll
        for (int j = 0; j < 6; j++) if (j < c && idx[j] == idx[c]) dup = true;
        if (dup) continue;   // uniform across workgroup

        __syncthreads();
        {
            const __bf16* kb = k + (plane + (size_t)idx[c] * BS_) * DH_;
            const __bf16* vb = vtb + (size_t)idx[c] * BS_;
            #pragma unroll
            for (int u = 0; u < 2; u++) {
                int ch = tid + u * 256;
                int row = ch >> 3, d0 = (ch & 7) * 8;
                *(bf16x8*)&Ks[row * KSTR + d0] = *(const bf16x8*)(kb + row * DH_ + d0);
                *(bf16x8*)&Vs[row * KSTR + d0] = *(const bf16x8*)(vb + (size_t)row * S_ + d0);
            }
        }
        __syncthreads();

        // ---- S^T = K·Q^T ----
        f32x4 st[4];
        #pragma unroll
        for (int t = 0; t < 4; t++) {
            bf16x8 ka0 = *(const bf16x8*)&Ks[(t * 16 + fr) * KSTR + fq * 8];
            bf16x8 ka1 = *(const bf16x8*)&Ks[(t * 16 + fr) * KSTR + 32 + fq * 8];
            st[t] = __builtin_amdgcn_mfma_f32_16x16x32_bf16(ka0, qf0, (f32x4){0.f,0.f,0.f,0.f}, 0, 0, 0);
            st[t] = __builtin_amdgcn_mfma_f32_16x16x32_bf16(ka1, qf1, st[t], 0, 0, 0);
        }
        float rmax = -1e30f;
        #pragma unroll
        for (int t = 0; t < 4; t++)
            #pragma unroll
            for (int i = 0; i < 4; i++) {
                st[t][i] *= 0.125f;
                rmax = fmaxf(rmax, st[t][i]);
            }
        rmax = fmaxf(rmax, __shfl_xor(rmax, 16));
        rmax = fmaxf(rmax, __shfl_xor(rmax, 32));
        float newm = fmaxf(mrow, rmax);
        float corr = __expf(mrow - newm);
        mrow = newm;
        float psum = 0.f;
        #pragma unroll
        for (int t = 0; t < 4; t++) {
            bf16x4 pk;
            #pragma unroll
            for (int i = 0; i < 4; i++) {
                float p = __expf(st[t][i] - newm);
                psum += p;
                pk[i] = (__bf16)p;
            }
            *(bf16x4*)&Ps[(wave * 16 + fr) * KSTR + t * 16 + fq * 4] = pk;
        }
        psum += __shfl_xor(psum, 16);
        psum += __shfl_xor(psum, 32);
        lrow = lrow * corr + psum;

        #pragma unroll
        for (int i = 0; i < 4; i++) {
            float ci = __shfl(corr, fq * 4 + i);
            #pragma unroll
            for (int dt = 0; dt < 4; dt++) oacc[dt][i] *= ci;
        }

        bf16x8 pa0 = *(const bf16x8*)&Ps[(wave * 16 + fr) * KSTR + fq * 8];
        bf16x8 pa1 = *(const bf16x8*)&Ps[(wave * 16 + fr) * KSTR + 32 + fq * 8];
        #pragma unroll
        for (int dt = 0; dt < 4; dt++) {
            bf16x8 vb0 = *(const bf16x8*)&Vs[(dt * 16 + fr) * KSTR + fq * 8];
            bf16x8 vb1 = *(const bf16x8*)&Vs[(dt * 16 + fr) * KSTR + 32 + fq * 8];
            oacc[dt] = __builtin_amdgcn_mfma_f32_16x16x32_bf16(pa0, vb0, oacc[dt], 0, 0, 0);
            oacc[dt] = __builtin_amdgcn_mfma_f32_16x16x32_bf16(pa1, vb1, oacc[dt], 0, 0, 0);
        }
    }

    float linv = 1.f / lrow;
    #pragma unroll
    for (int i = 0; i < 4; i++) {
        float li = __shfl(linv, fq * 4 + i);
        int s = n * BS_ + wave * 16 + fq * 4 + i;
        __bf16* op = o + ((size_t)b * S_ + s) * D_ + hh * DH_ + fr;
        #pragma unroll
        for (int dt = 0; dt < 4; dt++)
            op[dt * 16] = (__bf16)(oacc[dt][i] * li);
    }
}

// ---------------------------------------------------------------------------
// Fused residual-add + LayerNorm: h(fp32) += delta(bf16); LN; write h fp32
// and h_bf bf16. Stats in fp32. 256 thr = 4 rows/block.
// ---------------------------------------------------------------------------
__global__ __launch_bounds__(256) void ln_add_kernel(
    float* h, const __bf16* __restrict__ delta, __bf16* __restrict__ hb,
    const float* __restrict__ g, const float* __restrict__ bb)
{
    size_t r = (size_t)blockIdx.x * 4 + (threadIdx.x >> 6);
    int t = threadIdx.x & 63;
    float4* hp = (float4*)(h + r * D_) + 2 * t;
    float4 x0 = hp[0], x1 = hp[1];
    bf16x8 dv = *(const bf16x8*)&delta[r * D_ + t * 8];
    float x[8] = {x0.x, x0.y, x0.z, x0.w, x1.x, x1.y, x1.z, x1.w};
    #pragma unroll
    for (int j = 0; j < 8; j++) x[j] += (float)dv[j];
    float s = 0.f;
    #pragma unroll
    for (int j = 0; j < 8; j++) s += x[j];
    #pragma unroll
    for (int off = 32; off; off >>= 1) s += __shfl_xor(s, off, 64);
    float mean = s * (1.0f / D_);
    float ss = 0.f;
    #pragma unroll
    for (int j = 0; j < 8; j++) { x[j] -= mean; ss += x[j] * x[j]; }
    #pragma unroll
    for (int off = 32; off; off >>= 1) ss += __shfl_xor(ss, off, 64);
    float rs = rsqrtf(ss * (1.0f / D_) + 1e-5f);
    float4 g0 = ((const float4*)g)[2 * t], g1 = ((const float4*)g)[2 * t + 1];
    float4 b0 = ((const float4*)bb)[2 * t], b1 = ((const float4*)bb)[2 * t + 1];
    float gg[8] = {g0.x, g0.y, g0.z, g0.w, g1.x, g1.y, g1.z, g1.w};
    float bbv[8] = {b0.x, b0.y, b0.z, b0.w, b1.x, b1.y, b1.z, b1.w};
    float y[8];
    bf16x8 outv;
    #pragma unroll
    for (int j = 0; j < 8; j++) {
        y[j] = x[j] * rs * gg[j] + bbv[j];
        outv[j] = (__bf16)y[j];
    }
    hp[0] = (float4){y[0], y[1], y[2], y[3]};
    hp[1] = (float4){y[4], y[5], y[6], y[7]};
    *(bf16x8*)&hb[r * D_ + t * 8] = outv;
}

// ---------------------------------------------------------------------------
// Head stage 1: grid (8,4). Block (b,jg): columns j = jg*256 + tid of
// dense = relu(h[b,0,:] @ w_dense + b_dense); partial sums of dense@w_out.
// ---------------------------------------------------------------------------
__global__ __launch_bounds__(256) void head1_kernel(
    const float* __restrict__ h, const float* __restrict__ wd,
    const float* __restrict__ bd, const float* __restrict__ wo,
    float* __restrict__ partial)
{
    __shared__ float hrow[D_];
    __shared__ float red[8];
    int b = blockIdx.x, jg = blockIdx.y;
    int tid = threadIdx.x;
    if (tid < 128) ((float4*)hrow)[tid] = ((const float4*)(h + (size_t)b * S_ * D_))[tid];
    __syncthreads();
    int j = jg * 256 + tid;
    float acc = bd[j];
    #pragma unroll 8
    for (int i = 0; i < D_; i++) acc = fmaf(hrow[i], wd[(size_t)i * 1024 + j], acc);
    float dns = fmaxf(acc, 0.f);
    float2 w2 = ((const float2*)wo)[j];
    float p0 = dns * w2.x, p1 = dns * w2.y;
    #pragma unroll
    for (int off = 32; off; off >>= 1) { p0 += __shfl_xor(p0, off, 64); p1 += __shfl_xor(p1, off, 64); }
    int wid = tid >> 6;
    if ((tid & 63) == 0) { red[wid * 2] = p0; red[wid * 2 + 1] = p1; }
    __syncthreads();
    if (tid == 0) {
        float t0 = red[0] + red[2] + red[4] + red[6];
        float t1 = red[1] + red[3] + red[5] + red[7];
        partial[((size_t)b * 4 + jg) * 2 + 0] = t0;
        partial[((size_t)b * 4 + jg) * 2 + 1] = t1;
    }
}

// Head stage 2: 16 threads, one block.
__global__ __launch_bounds__(64) void head2_kernel(
    const float* __restrict__ partial, const float* __restrict__ bo,
    float* __restrict__ out)
{
    int tid = threadIdx.x;
    if (tid < 16) {
        int b = tid >> 1, c = tid & 1;
        float s = bo[c];
        #pragma unroll
        for (int jg = 0; jg < 4; jg++) s += partial[((size_t)b * 4 + jg) * 2 + c];
        out[b * 2 + c] = tanhf(s);
    }
}

// ---------------------------------------------------------------------------
extern "C" void kernel_launch(void* const* d_in, const int* in_sizes, int n_in,
                              void* d_out, int out_size, void* d_ws, size_t ws_size,
                              hipStream_t stream) {
    (void)in_sizes; (void)n_in; (void)out_size; (void)ws_size;
    const float* x       = (const float*)d_in[0];
    const float* w_embed = (const float*)d_in[1];
    const float* b_embed = (const float*)d_in[2];
    const float* pos_emb = (const float*)d_in[3];
    const float* Wq      = (const float*)d_in[4];
    const float* bq      = (const float*)d_in[5];
    const float* Wk      = (const float*)d_in[6];
    const float* bk      = (const float*)d_in[7];
    const float* Wv      = (const float*)d_in[8];
    const float* bv      = (const float*)d_in[9];
    const float* Wo      = (const float*)d_in[10];
    const float* bo      = (const float*)d_in[11];
    const float* ln1_g   = (const float*)d_in[12];
    const float* ln1_b   = (const float*)d_in[13];
    const float* W1      = (const float*)d_in[14];
    const float* b1      = (const float*)d_in[15];
    const float* W2      = (const float*)d_in[16];
    const float* b2      = (const float*)d_in[17];
    const float* ln2_g   = (const float*)d_in[18];
    const float* ln2_b   = (const float*)d_in[19];
    const float* w_dense = (const float*)d_in[20];
    const float* b_dense = (const float*)d_in[21];
    const float* w_out   = (const float*)d_in[22];
    const float* b_out   = (const float*)d_in[23];
    const int*   rb      = (const int*)d_in[24];
    float* out = (float*)d_out;

    // Workspace layout (~155 MiB):
    //  h fp32 32M @0 | h_bf 16M @32MiB | big 64M @48MiB: qkv(48M)+o(16M)==ff1
    //  (embed phase reuses big: xr, wt_e) | wt ~25M @112MiB | dbuf 16M @138MiB
    //  head partials @ 154 MiB
    const size_t PLANE = (size_t)B_ * H_ * S_ * DH_;  // 8,388,608
    float*  h    = (float*)d_ws;
    __bf16* h_bf = (__bf16*)((char*)d_ws + (size_t)32 * 1024 * 1024);
    __bf16* big  = (__bf16*)((char*)d_ws + (size_t)48 * 1024 * 1024);
    __bf16* qkv  = big;
    __bf16* o_bf = big + 3 * PLANE;
    __bf16* ff1  = big;                                // alias, lifetime-disjoint
    __bf16* xr   = big;                                // embed-phase only
    __bf16* wt_e = big + (size_t)28 * 1024 * 1024;     // embed-phase only (512*128)
    __bf16* wt   = (__bf16*)((char*)d_ws + (size_t)112 * 1024 * 1024);
    __bf16* wt_qkv = wt;                               // 3*L*D*D
    __bf16* wt_o   = wt_qkv + (size_t)3 * L_ * DD_;    // L*D*D
    __bf16* wt_1   = wt_o + (size_t)L_ * DD_;          // L*D*FF
    __bf16* wt_2   = wt_1 + (size_t)L_ * D_ * FF_;     // L*FF*D
    __bf16* dbuf   = (__bf16*)((char*)d_ws + (size_t)138 * 1024 * 1024); // 16M
    float*  hpart  = (float*)((char*)d_ws + (size_t)154 * 1024 * 1024);  // 64 floats

    dim3 tb(32, 8);
    wconv_qkvo<<<dim3(16, 16, 16), tb, 0, stream>>>(Wq, Wk, Wv, Wo, wt_qkv, wt_o);
    wconv_kernel<<<dim3(64, 16, L_), tb, 0, stream>>>(W1, wt_1, D_, FF_, D_);
    wconv_kernel<<<dim3(16, 64, L_), tb, 0, stream>>>(W2, wt_2, FF_, D_, FF_);
    wconv_kernel<<<dim3(16, 4, 1),  tb, 0, stream>>>(w_embed, wt_e, 80, D_, KE_);

    // Embed = MFMA GEMM: h/h_bf = xr @ wt_e^T + b_embed + pos_emb (cls -> pe[0])
    xbuild_kernel<<<MTOK / 64, 256, 0, stream>>>(x, xr);
    mfma_gemm<<<dim3(D_ / 128, MTOK / 256, 1), 512, 0, stream>>>(
        xr, wt_e, b_embed, b_embed, b_embed,
        pos_emb, h, h_bf, D_, KE_, 0, 0, 0, 0, 1);

    for (int l = 0; l < L_; l++) {
        // QKV (z folded into x for A-slice reuse; XCD swizzle in-kernel)
        mfma_gemm<<<dim3((D_ / 128) * 3, MTOK / 256, 1), 512, 0, stream>>>(
            h_bf, wt_qkv + (size_t)l * DD_, bq + l * D_, bk + l * D_, bv + l * D_,
            nullptr, nullptr, qkv, D_, D_, (long)L_ * DD_, (long)PLANE, 0, 1, 3);

        attn_kernel<<<B_ * H_ * NB_, 256, 0, stream>>>(qkv, qkv + PLANE, qkv + 2 * PLANE, rb, o_bf);

        // dbuf = o @ Wo + bo  (delta only, bf16)
        mfma_gemm<<<dim3(D_ / 128, MTOK / 256, 1), 512, 0, stream>>>(
            o_bf, wt_o + (size_t)l * DD_, bo + l * D_, bo + l * D_, bo + l * D_,
            nullptr, nullptr, dbuf, D_, D_, 0, 0, 0, 0, 1);
        // h += dbuf; LN -> h (fp32) + h_bf (bf16)
        ln_add_kernel<<<MTOK / 4, 256, 0, stream>>>(h, dbuf, h_bf, ln1_g + l * D_, ln1_b + l * D_);

        // ff1 = relu(h @ W1 + b1)
        mfma_gemm<<<dim3(FF_ / 128, MTOK / 256, 1), 512, 0, stream>>>(
            h_bf, wt_1 + (size_t)l * D_ * FF_, b1 + l * FF_, b1 + l * FF_, b1 + l * FF_,
            nullptr, nullptr, ff1, FF_, D_, 0, 0, 1, 0, 1);

        // dbuf = ff1 @ W2 + b2  (delta only, bf16)
        mfma_gemm<<<dim3(D_ / 128, MTOK / 256, 1), 512, 0, stream>>>(
            ff1, wt_2 + (size_t)l * FF_ * D_, b2 + l * D_, b2 + l * D_, b2 + l * D_,
            nullptr, nullptr, dbuf, D_, FF_, 0, 0, 0, 0, 1);
        ln_add_kernel<<<MTOK / 4, 256, 0, stream>>>(h, dbuf, h_bf, ln2_g + l * D_, ln2_b + l * D_);
    }

    head1_kernel<<<dim3(B_, 4), 256, 0, stream>>>(h, w_dense, b_dense, w_out, hpart);
    head2_kernel<<<1, 64, 0, stream>>>(hpart, b_out, out);
}

// Round 2
// 983.444 us; speedup vs baseline: 1.2379x; 1.2379x over previous
//
#include <hip/hip_runtime.h>
#include <cstdint>
#include <cstddef>

// Problem constants
#define B_   8
#define NM_  10
#define T_   16376
#define D_   512
#define H_   8
#define DH_  64
#define L_   4
#define S_   2048
#define NB_  32
#define BS_  64
#define FF_  2048
#define MTOK (B_*S_)   // 16384 token rows
#define DD_  (D_*D_)
#define KE_  128       // embed K padded (80 -> 128, divisible by BK=64)

typedef __attribute__((ext_vector_type(8))) __bf16 bf16x8;
typedef __attribute__((ext_vector_type(4))) __bf16 bf16x4;
typedef __attribute__((ext_vector_type(4))) float f32x4;

__device__ __forceinline__ void async16(void* lds, const void* g) {
    __builtin_amdgcn_global_load_lds(
        (const __attribute__((address_space(1))) void*)g,
        (__attribute__((address_space(3))) void*)lds, 16, 0, 0);
}

// XOR-swizzled 16B-chunk index for a 128row x 64el bf16 tile (8 chunks/row).
#define SWZ64(row, kq) (((row) << 3) + ((kq) ^ ((row) & 7)))

// ---------------------------------------------------------------------------
// Weight transpose+convert: in (K x N fp32) -> out (N x Kp bf16), zero-pad
// k in [K, Kp). Grid: (N/32, Kp/32, Z) with z-strided in/out.
// ---------------------------------------------------------------------------
__global__ __launch_bounds__(256) void wconv_kernel(
    const float* __restrict__ in, __bf16* __restrict__ outp, int K, int N, int Kp)
{
    __shared__ float t[32][33];
    const float* ip = in + (size_t)blockIdx.z * K * N;
    __bf16* op = outp + (size_t)blockIdx.z * N * Kp;
    int n0 = blockIdx.x * 32, k0 = blockIdx.y * 32;
    int tx = threadIdx.x, ty = threadIdx.y;   // 32 x 8
    #pragma unroll
    for (int j = 0; j < 4; j++) {
        int k = k0 + ty + 8 * j;
        t[ty + 8 * j][tx] = (k < K) ? ip[(size_t)k * N + n0 + tx] : 0.f;
    }
    __syncthreads();
    #pragma unroll
    for (int j = 0; j < 4; j++)
        op[(size_t)(n0 + ty + 8 * j) * Kp + k0 + tx] = (__bf16)t[tx][ty + 8 * j];
}

// Merged Wq/Wk/Wv/Wo transpose (all D_ x D_). Grid (16,16,16): z = mat*4+layer.
__global__ __launch_bounds__(256) void wconv_qkvo(
    const float* __restrict__ wq, const float* __restrict__ wk,
    const float* __restrict__ wv, const float* __restrict__ wo,
    __bf16* __restrict__ wtqkv, __bf16* __restrict__ wto)
{
    __shared__ float t[32][33];
    int zz = blockIdx.z;
    int mat = zz >> 2, layer = zz & 3;
    const float* src = (mat == 0 ? wq : mat == 1 ? wk : mat == 2 ? wv : wo)
                       + (size_t)layer * DD_;
    __bf16* dst = (mat < 3) ? wtqkv + ((size_t)mat * L_ + layer) * DD_
                            : wto + (size_t)layer * DD_;
    int n0 = blockIdx.x * 32, k0 = blockIdx.y * 32;
    int tx = threadIdx.x, ty = threadIdx.y;   // 32 x 8
    #pragma unroll
    for (int j = 0; j < 4; j++)
        t[ty + 8 * j][tx] = src[(size_t)(k0 + ty + 8 * j) * D_ + n0 + tx];
    __syncthreads();
    #pragma unroll
    for (int j = 0; j < 4; j++)
        dst[(size_t)(n0 + ty + 8 * j) * D_ + k0 + tx] = (__bf16)t[tx][ty + 8 * j];
}

// ---------------------------------------------------------------------------
// Build xr (MTOK x KE_ bf16): xr[b*2048+t][m] = x[b, m/8, (m%8)*2047 + t-1]
// for t>=1, m<80; else 0. One block per 64 rows (same b).
// ---------------------------------------------------------------------------
__global__ __launch_bounds__(256) void xbuild_kernel(
    const float* __restrict__ x, __bf16* __restrict__ xr)
{
    __shared__ float xs[64][KE_ + 1];
    int row0 = blockIdx.x * 64;
    int b = row0 >> 11;
    int t0 = row0 & (S_ - 1);
    int tid = threadIdx.x;
    int lane = tid & 63;
    int mq = tid >> 6;          // 0..3
    for (int mb = 0; mb < 32; mb++) {
        int m = mb * 4 + mq;    // 0..127
        int t = t0 + lane;
        float v = 0.f;
        if (m < 80 && t > 0)
            v = x[(size_t)b * NM_ * T_ + (size_t)(m >> 3) * T_ + (m & 7) * 2047 + (t - 1)];
        xs[lane][m] = v;
    }
    __syncthreads();
    #pragma unroll
    for (int u = 0; u < 8; u++) {
        int ch = tid + u * 256;          // 0..2047
        int row = ch >> 5, c4 = (ch & 31) * 4;
        bf16x4 pk;
        #pragma unroll
        for (int i = 0; i < 4; i++) pk[i] = (__bf16)xs[row][c4 + i];
        *(bf16x4*)&xr[(size_t)(row0 + row) * KE_ + c4] = pk;
    }
}

// ---------------------------------------------------------------------------
// MFMA bf16 GEMM: C = A(MxK bf16) @ Wt^T + bias [+pe] [relu]
// Wt is N x K bf16 (pre-transposed). 128x128 tile, BK=64, 512 thr (8 waves,
// each owning a 64x32 output sub-tile). LDS stays 64 KiB -> 2 blocks/CU ->
// 16 waves/CU (4/SIMD) for cross-block latency hiding of the 2-phase drain.
// Double-buffered LDS + XOR swizzle (conflict-free ds_read_b128).
// z folded into x; XCD-aware swizzle: each XCD owns a contiguous bm band.
// Outputs: Cf fp32 (optional) and/or Cb bf16 (optional).
// scatter==1: z in {0,1} -> (B,H,S,DH); z==2 -> V transposed (B,H,DH,S).
// pe != null: val += pe[(row&2047)*N + col]; row with t==0 -> val = pe[col].
// ---------------------------------------------------------------------------
__global__ __launch_bounds__(512, 4) void mfma_gemm(
    const __bf16* __restrict__ A, const __bf16* __restrict__ Wt,
    const float* __restrict__ bias0, const float* __restrict__ bias1,
    const float* __restrict__ bias2,
    const float* __restrict__ pe, float* __restrict__ Cf, __bf16* __restrict__ Cb,
    int N, int K, long wtz, long cbz, int relu, int scatter, int nz)
{
    __shared__ __align__(16) __bf16 As[2][128 * 64];
    __shared__ __align__(16) __bf16 Bs[2][128 * 64];
    int tid = threadIdx.x;
    int wave = tid >> 6;    // 0..7
    int lane = tid & 63;

    int nbx = gridDim.x, nby = gridDim.y;
    int bxIdx, bmIdx;
    if ((nby & 7) == 0) {
        int id = blockIdx.y * nbx + blockIdx.x;   // dispatch-linear order
        int chunk = nby >> 3;
        int xcd = id & 7;
        int local = id >> 3;
        int row = local / nbx;
        bmIdx = xcd * chunk + row;
        bxIdx = local - row * nbx;
    } else {
        bxIdx = blockIdx.x; bmIdx = blockIdx.y;
    }
    int z = bxIdx % nz;
    int bn = (bxIdx / nz) * 128;
    int bm = bmIdx * 128;
    const __bf16* Wz = Wt + (size_t)z * wtz;
    const float* bias = (z == 0) ? bias0 : (z == 1 ? bias1 : bias2);

    f32x4 acc[4][2];
    #pragma unroll
    for (int r = 0; r < 4; r++)
        #pragma unroll
        for (int c = 0; c < 2; c++) acc[r][c] = (f32x4){0.f, 0.f, 0.f, 0.f};

    const int wr = (wave >> 2) * 64;   // row band: 0 / 64
    const int wc = (wave & 3) * 32;    // col band: 0/32/64/96
    const int fr = lane & 15;
    const int kqi = lane >> 4;   // 0..3

    // staging: pre-swizzled global source, linear LDS dest (wave-uniform base)
    const __bf16* pA[2];
    const __bf16* pB[2];
    int ldsoff[2];
    #pragma unroll
    for (int u = 0; u < 2; u++) {
        int p = tid + 512 * u;          // chunk 0..1023 (128 rows x 8 chunks)
        int row = p >> 3;
        int kq = (p & 7) ^ (row & 7);
        pA[u] = A  + (size_t)(bm + row) * K + kq * 8;
        pB[u] = Wz + (size_t)(bn + row) * K + kq * 8;
        ldsoff[u] = (u * 512 + wave * 64) * 8;
    }

    __bf16 *a_cur = As[0], *a_nxt = As[1];
    __bf16 *b_cur = Bs[0], *b_nxt = Bs[1];

    #pragma unroll
    for (int u = 0; u < 2; u++) {
        async16(a_cur + ldsoff[u], pA[u]);
        async16(b_cur + ldsoff[u], pB[u]);
    }

    for (int kk = 0; kk < K; kk += 64) {
        __syncthreads();
        if (kk + 64 < K) {
            #pragma unroll
            for (int u = 0; u < 2; u++) {
                async16(a_nxt + ldsoff[u], pA[u] + kk + 64);
                async16(b_nxt + ldsoff[u], pB[u] + kk + 64);
            }
        }
        #pragma unroll
        for (int ks = 0; ks < 2; ks++) {
            int kq0 = ks * 4 + kqi;
            bf16x8 af[4], bfr[2];
            #pragma unroll
            for (int r = 0; r < 4; r++)
                af[r] = *(const bf16x8*)&a_cur[SWZ64(wr + r * 16 + fr, kq0) * 8];
            #pragma unroll
            for (int c = 0; c < 2; c++)
                bfr[c] = *(const bf16x8*)&b_cur[SWZ64(wc + c * 16 + fr, kq0) * 8];
            #pragma unroll
            for (int r = 0; r < 4; r++)
                #pragma unroll
                for (int c = 0; c < 2; c++)
                    acc[r][c] = __builtin_amdgcn_mfma_f32_16x16x32_bf16(af[r], bfr[c], acc[r][c], 0, 0, 0);
        }
        __bf16* t;
        t = a_cur; a_cur = a_nxt; a_nxt = t;
        t = b_cur; b_cur = b_nxt; b_nxt = t;
    }

    // epilogue: C/D layout col = lane&15, row = (lane>>4)*4 + reg
    int rbase = bm + wr + (lane >> 4) * 4;
    #pragma unroll
    for (int c = 0; c < 2; c++) {
        int cg = bn + wc + c * 16 + fr;
        float bv = bias[cg];
        #pragma unroll
        for (int r = 0; r < 4; r++) {
            int rg0 = rbase + r * 16;   // 4-aligned
            float vals[4];
            #pragma unroll
            for (int i = 0; i < 4; i++) {
                float val = acc[r][c][i] + bv;
                if (relu) val = fmaxf(val, 0.f);
                if (pe) {
                    int t = (rg0 + i) & (S_ - 1);
                    val = (t == 0) ? pe[cg] : val + pe[(size_t)t * N + cg];
                }
                vals[i] = val;
            }
            if (Cf) {
                #pragma unroll
                for (int i = 0; i < 4; i++) Cf[(size_t)(rg0 + i) * N + cg] = vals[i];
            }
            if (Cb) {
                if (scatter) {
                    int bb = rg0 >> 11;
                    int s0 = rg0 & (S_ - 1);
                    int hh = cg >> 6, dh = cg & 63;
                    if (z == 2) {
                        bf16x4 pk;
                        #pragma unroll
                        for (int i = 0; i < 4; i++) pk[i] = (__bf16)vals[i];
                        *(bf16x4*)(Cb + (size_t)z * cbz +
                                   ((((size_t)bb * H_ + hh) * DH_ + dh) * S_) + s0) = pk;
                    } else {
                        #pragma unroll
                        for (int i = 0; i < 4; i++)
                            (Cb + (size_t)z * cbz)[((((size_t)bb * H_ + hh) * S_ + s0 + i) * DH_) + dh] = (__bf16)vals[i];
                    }
                } else {
                    #pragma unroll
                    for (int i = 0; i < 4; i++) Cb[(size_t)(rg0 + i) * N + cg] = (__bf16)vals[i];
                }
            }
        }
    }
}

// ---------------------------------------------------------------------------
// MFMA block-sparse attention. One workgroup (4 waves) per (b,h,n); each wave
// owns 16 q-rows. XCD affinity: all 32 n-blocks of one (b,h) on one XCD.
// ---------------------------------------------------------------------------
#define KSTR 72
__global__ __launch_bounds__(256, 4) void attn_kernel(
    const __bf16* __restrict__ q, const __bf16* __restrict__ k,
    const __bf16* __restrict__ vt, const int* __restrict__ rb,
    __bf16* __restrict__ o)
{
    __shared__ __align__(16) __bf16 Ks[64 * KSTR];
    __shared__ __align__(16) __bf16 Vs[64 * KSTR];
    __shared__ __align__(16) __bf16 Ps[64 * KSTR];
    int bid = blockIdx.x;                 // 2048
    int xcd = bid & 7;
    int local = bid >> 3;                 // 0..255
    int bh = (local >> 5) * 8 + xcd;      // 0..63, fixed per XCD
    int n = local & 31;
    int b = bh >> 3;
    int hh = bh & 7;
    int tid = threadIdx.x;
    int wave = tid >> 6;
    int lane = tid & 63;
    const int fr = lane & 15;
    const int fq = lane >> 4;

    int idx[6];
    idx[0] = 0;
    idx[1] = n > 0 ? n - 1 : 0;
    idx[2] = n;
    idx[3] = n < NB_ - 1 ? n + 1 : NB_ - 1;
    idx[4] = rb[n * 2 + 0];
    idx[5] = rb[n * 2 + 1];

    const size_t plane = ((size_t)b * H_ + hh) * S_;
    const __bf16* vtb = vt + plane * DH_;

    const __bf16* qrow = q + (plane + (size_t)n * BS_ + wave * 16 + fr) * DH_ + fq * 8;
    bf16x8 qf0 = *(const bf16x8*)qrow;
    bf16x8 qf1 = *(const bf16x8*)(qrow + 32);

    f32x4 oacc[4];
    #pragma unroll
    for (int dt = 0; dt < 4; dt++) oacc[dt] = (f32x4){0.f, 0.f, 0.f, 0.f};
    float mrow = -1e30f, lrow = 0.f;

    for (int c = 0; c < 6; c++) {
        bool dup = false;
        #pragma unroll
        for (int j = 0; j < 6; j++) if (j < c && idx[j] == idx[c]) dup = true;
        if (dup) continue;   // uniform across workgroup

        __syncthreads();
        {
            const __bf16* kb = k + (plane + (size_t)idx[c] * BS_) * DH_;
            const __bf16* vb = vtb + (size_t)idx[c] * BS_;
            #pragma unroll
            for (int u = 0; u < 2; u++) {
                int ch = tid + u * 256;
                int row = ch >> 3, d0 = (ch & 7) * 8;
                *(bf16x8*)&Ks[row * KSTR + d0] = *(const bf16x8*)(kb + row * DH_ + d0);
                *(bf16x8*)&Vs[row * KSTR + d0] = *(const bf16x8*)(vb + (size_t)row * S_ + d0);
            }
        }
        __syncthreads();

        // ---- S^T = K·Q^T ----
        f32x4 st[4];
        #pragma unroll
        for (int t = 0; t < 4; t++) {
            bf16x8 ka0 = *(const bf16x8*)&Ks[(t * 16 + fr) * KSTR + fq * 8];
            bf16x8 ka1 = *(const bf16x8*)&Ks[(t * 16 + fr) * KSTR + 32 + fq * 8];
            st[t] = __builtin_amdgcn_mfma_f32_16x16x32_bf16(ka0, qf0, (f32x4){0.f,0.f,0.f,0.f}, 0, 0, 0);
            st[t] = __builtin_amdgcn_mfma_f32_16x16x32_bf16(ka1, qf1, st[t], 0, 0, 0);
        }
        float rmax = -1e30f;
        #pragma unroll
        for (int t = 0; t < 4; t++)
            #pragma unroll
            for (int i = 0; i < 4; i++) {
                st[t][i] *= 0.125f;
                rmax = fmaxf(rmax, st[t][i]);
            }
        rmax = fmaxf(rmax, __shfl_xor(rmax, 16));
        rmax = fmaxf(rmax, __shfl_xor(rmax, 32));
        float newm = fmaxf(mrow, rmax);
        float corr = __expf(mrow - newm);
        mrow = newm;
        float psum = 0.f;
        #pragma unroll
        for (int t = 0; t < 4; t++) {
            bf16x4 pk;
            #pragma unroll
            for (int i = 0; i < 4; i++) {
                float p = __expf(st[t][i] - newm);
                psum += p;
                pk[i] = (__bf16)p;
            }
            *(bf16x4*)&Ps[(wave * 16 + fr) * KSTR + t * 16 + fq * 4] = pk;
        }
        psum += __shfl_xor(psum, 16);
        psum += __shfl_xor(psum, 32);
        lrow = lrow * corr + psum;

        #pragma unroll
        for (int i = 0; i < 4; i++) {
            float ci = __shfl(corr, fq * 4 + i);
            #pragma unroll
            for (int dt = 0; dt < 4; dt++) oacc[dt][i] *= ci;
        }

        bf16x8 pa0 = *(const bf16x8*)&Ps[(wave * 16 + fr) * KSTR + fq * 8];
        bf16x8 pa1 = *(const bf16x8*)&Ps[(wave * 16 + fr) * KSTR + 32 + fq * 8];
        #pragma unroll
        for (int dt = 0; dt < 4; dt++) {
            bf16x8 vb0 = *(const bf16x8*)&Vs[(dt * 16 + fr) * KSTR + fq * 8];
            bf16x8 vb1 = *(const bf16x8*)&Vs[(dt * 16 + fr) * KSTR + 32 + fq * 8];
            oacc[dt] = __builtin_amdgcn_mfma_f32_16x16x32_bf16(pa0, vb0, oacc[dt], 0, 0, 0);
            oacc[dt] = __builtin_amdgcn_mfma_f32_16x16x32_bf16(pa1, vb1, oacc[dt], 0, 0, 0);
        }
    }

    float linv = 1.f / lrow;
    #pragma unroll
    for (int i = 0; i < 4; i++) {
        float li = __shfl(linv, fq * 4 + i);
        int s = n * BS_ + wave * 16 + fq * 4 + i;
        __bf16* op = o + ((size_t)b * S_ + s) * D_ + hh * DH_ + fr;
        #pragma unroll
        for (int dt = 0; dt < 4; dt++)
            op[dt * 16] = (__bf16)(oacc[dt][i] * li);
    }
}

// ---------------------------------------------------------------------------
// Fused residual-add + LayerNorm: h(fp32) += delta(bf16); LN; write h fp32
// and h_bf bf16. Stats in fp32. 256 thr = 4 rows/block.
// ---------------------------------------------------------------------------
__global__ __launch_bounds__(256) void ln_add_kernel(
    float* h, const __bf16* __restrict__ delta, __bf16* __restrict__ hb,
    const float* __restrict__ g, const float* __restrict__ bb)
{
    size_t r = (size_t)blockIdx.x * 4 + (threadIdx.x >> 6);
    int t = threadIdx.x & 63;
    float4* hp = (float4*)(h + r * D_) + 2 * t;
    float4 x0 = hp[0], x1 = hp[1];
    bf16x8 dv = *(const bf16x8*)&delta[r * D_ + t * 8];
    float x[8] = {x0.x, x0.y, x0.z, x0.w, x1.x, x1.y, x1.z, x1.w};
    #pragma unroll
    for (int j = 0; j < 8; j++) x[j] += (float)dv[j];
    float s = 0.f;
    #pragma unroll
    for (int j = 0; j < 8; j++) s += x[j];
    #pragma unroll
    for (int off = 32; off; off >>= 1) s += __shfl_xor(s, off, 64);
    float mean = s * (1.0f / D_);
    float ss = 0.f;
    #pragma unroll
    for (int j = 0; j < 8; j++) { x[j] -= mean; ss += x[j] * x[j]; }
    #pragma unroll
    for (int off = 32; off; off >>= 1) ss += __shfl_xor(ss, off, 64);
    float rs = rsqrtf(ss * (1.0f / D_) + 1e-5f);
    float4 g0 = ((const float4*)g)[2 * t], g1 = ((const float4*)g)[2 * t + 1];
    float4 b0 = ((const float4*)bb)[2 * t], b1 = ((const float4*)bb)[2 * t + 1];
    float gg[8] = {g0.x, g0.y, g0.z, g0.w, g1.x, g1.y, g1.z, g1.w};
    float bbv[8] = {b0.x, b0.y, b0.z, b0.w, b1.x, b1.y, b1.z, b1.w};
    float y[8];
    bf16x8 outv;
    #pragma unroll
    for (int j = 0; j < 8; j++) {
        y[j] = x[j] * rs * gg[j] + bbv[j];
        outv[j] = (__bf16)y[j];
    }
    hp[0] = (float4){y[0], y[1], y[2], y[3]};
    hp[1] = (float4){y[4], y[5], y[6], y[7]};
    *(bf16x8*)&hb[r * D_ + t * 8] = outv;
}

// ---------------------------------------------------------------------------
// Head stage 1: grid (8,4). Block (b,jg): columns j = jg*256 + tid of
// dense = relu(h[b,0,:] @ w_dense + b_dense); partial sums of dense@w_out.
// ---------------------------------------------------------------------------
__global__ __launch_bounds__(256) void head1_kernel(
    const float* __restrict__ h, const float* __restrict__ wd,
    const float* __restrict__ bd, const float* __restrict__ wo,
    float* __restrict__ partial)
{
    __shared__ float hrow[D_];
    __shared__ float red[8];
    int b = blockIdx.x, jg = blockIdx.y;
    int tid = threadIdx.x;
    if (tid < 128) ((float4*)hrow)[tid] = ((const float4*)(h + (size_t)b * S_ * D_))[tid];
    __syncthreads();
    int j = jg * 256 + tid;
    float acc = bd[j];
    #pragma unroll 8
    for (int i = 0; i < D_; i++) acc = fmaf(hrow[i], wd[(size_t)i * 1024 + j], acc);
    float dns = fmaxf(acc, 0.f);
    float2 w2 = ((const float2*)wo)[j];
    float p0 = dns * w2.x, p1 = dns * w2.y;
    #pragma unroll
    for (int off = 32; off; off >>= 1) { p0 += __shfl_xor(p0, off, 64); p1 += __shfl_xor(p1, off, 64); }
    int wid = tid >> 6;
    if ((tid & 63) == 0) { red[wid * 2] = p0; red[wid * 2 + 1] = p1; }
    __syncthreads();
    if (tid == 0) {
        float t0 = red[0] + red[2] + red[4] + red[6];
        float t1 = red[1] + red[3] + red[5] + red[7];
        partial[((size_t)b * 4 + jg) * 2 + 0] = t0;
        partial[((size_t)b * 4 + jg) * 2 + 1] = t1;
    }
}

// Head stage 2: 16 threads, one block.
__global__ __launch_bounds__(64) void head2_kernel(
    const float* __restrict__ partial, const float* __restrict__ bo,
    float* __restrict__ out)
{
    int tid = threadIdx.x;
    if (tid < 16) {
        int b = tid >> 1, c = tid & 1;
        float s = bo[c];
        #pragma unroll
        for (int jg = 0; jg < 4; jg++) s += partial[((size_t)b * 4 + jg) * 2 + c];
        out[b * 2 + c] = tanhf(s);
    }
}

// ---------------------------------------------------------------------------
extern "C" void kernel_launch(void* const* d_in, const int* in_sizes, int n_in,
                              void* d_out, int out_size, void* d_ws, size_t ws_size,
                              hipStream_t stream) {
    (void)in_sizes; (void)n_in; (void)out_size; (void)ws_size;
    const float* x       = (const float*)d_in[0];
    const float* w_embed = (const float*)d_in[1];
    const float* b_embed = (const float*)d_in[2];
    const float* pos_emb = (const float*)d_in[3];
    const float* Wq      = (const float*)d_in[4];
    const float* bq      = (const float*)d_in[5];
    const float* Wk      = (const float*)d_in[6];
    const float* bk      = (const float*)d_in[7];
    const float* Wv      = (const float*)d_in[8];
    const float* bv      = (const float*)d_in[9];
    const float* Wo      = (const float*)d_in[10];
    const float* bo      = (const float*)d_in[11];
    const float* ln1_g   = (const float*)d_in[12];
    const float* ln1_b   = (const float*)d_in[13];
    const float* W1      = (const float*)d_in[14];
    const float* b1      = (const float*)d_in[15];
    const float* W2      = (const float*)d_in[16];
    const float* b2      = (const float*)d_in[17];
    const float* ln2_g   = (const float*)d_in[18];
    const float* ln2_b   = (const float*)d_in[19];
    const float* w_dense = (const float*)d_in[20];
    const float* b_dense = (const float*)d_in[21];
    const float* w_out   = (const float*)d_in[22];
    const float* b_out   = (const float*)d_in[23];
    const int*   rb      = (const int*)d_in[24];
    float* out = (float*)d_out;

    // Workspace layout (~155 MiB):
    //  h fp32 32M @0 | h_bf 16M @32MiB | big 64M @48MiB: qkv(48M)+o(16M)==ff1
    //  (embed phase reuses big: xr, wt_e) | wt ~25M @112MiB | dbuf 16M @138MiB
    //  head partials @ 154 MiB
    const size_t PLANE = (size_t)B_ * H_ * S_ * DH_;  // 8,388,608
    float*  h    = (float*)d_ws;
    __bf16* h_bf = (__bf16*)((char*)d_ws + (size_t)32 * 1024 * 1024);
    __bf16* big  = (__bf16*)((char*)d_ws + (size_t)48 * 1024 * 1024);
    __bf16* qkv  = big;
    __bf16* o_bf = big + 3 * PLANE;
    __bf16* ff1  = big;                                // alias, lifetime-disjoint
    __bf16* xr   = big;                                // embed-phase only
    __bf16* wt_e = big + (size_t)28 * 1024 * 1024;     // embed-phase only (512*128)
    __bf16* wt   = (__bf16*)((char*)d_ws + (size_t)112 * 1024 * 1024);
    __bf16* wt_qkv = wt;                               // 3*L*D*D
    __bf16* wt_o   = wt_qkv + (size_t)3 * L_ * DD_;    // L*D*D
    __bf16* wt_1   = wt_o + (size_t)L_ * DD_;          // L*D*FF
    __bf16* wt_2   = wt_1 + (size_t)L_ * D_ * FF_;     // L*FF*D
    __bf16* dbuf   = (__bf16*)((char*)d_ws + (size_t)138 * 1024 * 1024); // 16M
    float*  hpart  = (float*)((char*)d_ws + (size_t)154 * 1024 * 1024);  // 64 floats

    dim3 tb(32, 8);
    wconv_qkvo<<<dim3(16, 16, 16), tb, 0, stream>>>(Wq, Wk, Wv, Wo, wt_qkv, wt_o);
    wconv_kernel<<<dim3(64, 16, L_), tb, 0, stream>>>(W1, wt_1, D_, FF_, D_);
    wconv_kernel<<<dim3(16, 64, L_), tb, 0, stream>>>(W2, wt_2, FF_, D_, FF_);
    wconv_kernel<<<dim3(16, 4, 1),  tb, 0, stream>>>(w_embed, wt_e, 80, D_, KE_);

    // Embed = MFMA GEMM: h/h_bf = xr @ wt_e^T + b_embed + pos_emb (cls -> pe[0])
    xbuild_kernel<<<MTOK / 64, 256, 0, stream>>>(x, xr);
    mfma_gemm<<<dim3(D_ / 128, MTOK / 128, 1), 512, 0, stream>>>(
        xr, wt_e, b_embed, b_embed, b_embed,
        pos_emb, h, h_bf, D_, KE_, 0, 0, 0, 0, 1);

    for (int l = 0; l < L_; l++) {
        // QKV (z folded into x for A-slice reuse; XCD swizzle in-kernel)
        mfma_gemm<<<dim3((D_ / 128) * 3, MTOK / 128, 1), 512, 0, stream>>>(
            h_bf, wt_qkv + (size_t)l * DD_, bq + l * D_, bk + l * D_, bv + l * D_,
            nullptr, nullptr, qkv, D_, D_, (long)L_ * DD_, (long)PLANE, 0, 1, 3);

        attn_kernel<<<B_ * H_ * NB_, 256, 0, stream>>>(qkv, qkv + PLANE, qkv + 2 * PLANE, rb, o_bf);

        // dbuf = o @ Wo + bo  (delta only, bf16)
        mfma_gemm<<<dim3(D_ / 128, MTOK / 128, 1), 512, 0, stream>>>(
            o_bf, wt_o + (size_t)l * DD_, bo + l * D_, bo + l * D_, bo + l * D_,
            nullptr, nullptr, dbuf, D_, D_, 0, 0, 0, 0, 1);
        // h += dbuf; LN -> h (fp32) + h_bf (bf16)
        ln_add_kernel<<<MTOK / 4, 256, 0, stream>>>(h, dbuf, h_bf, ln1_g + l * D_, ln1_b + l * D_);

        // ff1 = relu(h @ W1 + b1)
        mfma_gemm<<<dim3(FF_ / 128, MTOK / 128, 1), 512, 0, stream>>>(
            h_bf, wt_1 + (size_t)l * D_ * FF_, b1 + l * FF_, b1 + l * FF_, b1 + l * FF_,
            nullptr, nullptr, ff1, FF_, D_, 0, 0, 1, 0, 1);

        // dbuf = ff1 @ W2 + b2  (delta only, bf16)
        mfma_gemm<<<dim3(D_ / 128, MTOK / 128, 1), 512, 0, stream>>>(
            ff1, wt_2 + (size_t)l * FF_ * D_, b2 + l * D_, b2 + l * D_, b2 + l * D_,
            nullptr, nullptr, dbuf, D_, FF_, 0, 0, 0, 0, 1);
        ln_add_kernel<<<MTOK / 4, 256, 0, stream>>>(h, dbuf, h_bf, ln2_g + l * D_, ln2_b + l * D_);
    }

    head1_kernel<<<dim3(B_, 4), 256, 0, stream>>>(h, w_dense, b_dense, w_out, hpart);
    head2_kernel<<<1, 64, 0, stream>>>(hpart, b_out, out);
}